// Round 4
// baseline (1553.274 us; speedup 1.0000x reference)
//
#include <hip/hip_runtime.h>
#include <hip/hip_cooperative_groups.h>
#include <math.h>

namespace cg = cooperative_groups;

// Problem dims
#define HD    2048
#define QKVD  8192
#define TVD   4096
#define NVHD  32
#define KDD   128
#define VDD   128
#define PROJN (QKVD + TVD + 2*NVHD)   // 12352
#define NB    1024
#define BT    256

typedef float f4 __attribute__((ext_vector_type(4)));

// ---------- helpers ----------
__device__ __forceinline__ float sigmoidf_(float x) { return 1.0f / (1.0f + expf(-x)); }
__device__ __forceinline__ float siluf_(float x)    { return x / (1.0f + expf(-x)); }
__device__ __forceinline__ float softplusf_(float x){ return (x > 20.0f) ? x : log1pf(expf(x)); }
__device__ __forceinline__ float dot4(f4 a, f4 b)   { return a.x*b.x + a.y*b.y + a.z*b.z + a.w*b.w; }
__device__ __forceinline__ f4 ntload(const f4* p)   { return __builtin_nontemporal_load(p); }

__device__ __forceinline__ float waveReduceSum(float v) {
#pragma unroll
    for (int o = 32; o > 0; o >>= 1) v += __shfl_down(v, o, 64);
    return v;
}

template<int NW>
__device__ __forceinline__ float blockReduceSum(float v, float* red) {
    const int lane = threadIdx.x & 63, wid = threadIdx.x >> 6;
    v = waveReduceSum(v);
    if (lane == 0) red[wid] = v;
    __syncthreads();
    float s = 0.f;
#pragma unroll
    for (int w = 0; w < NW; w++) s += red[w];
    __syncthreads();
    return s;
}

// ================= cooperative mega-kernel =================
__global__ __launch_bounds__(BT, 4)
void mega(const float* __restrict__ x, const float* __restrict__ conv_state,
          const float* __restrict__ ssm_state, const float* __restrict__ in_proj_w,
          const float* __restrict__ out_proj_w, const float* __restrict__ conv_weight,
          const float* __restrict__ A_log, const float* __restrict__ dt_bias,
          const float* __restrict__ norm_weight, const float* __restrict__ rms1_w,
          const float* __restrict__ rms2_w, const float* __restrict__ gate_w,
          const float* __restrict__ up_w, const float* __restrict__ down_w,
          float* __restrict__ out0, float* __restrict__ new_conv,
          float* __restrict__ new_ssm, float* __restrict__ proj,
          float* __restrict__ yout, float* __restrict__ x1, float* __restrict__ mmid) {
    cg::grid_group grid = cg::this_grid();
    __shared__ float smem[HD];     // aliased per phase: hl / ssm arrays / tl
    __shared__ float red[8];
    __shared__ float part[4];
    const int t = threadIdx.x, bid = blockIdx.x;
    const int wid = t >> 6, lane = t & 63;

    // ---- P0: rms1 -> smem (per-block copy; x,w1 are L2-hot 8KB) ----
    {
        f4 xv[2];
        float s = 0.f;
#pragma unroll
        for (int i = 0; i < 2; i++) {
            xv[i] = ((const f4*)x)[t + i*256];
            s += dot4(xv[i], xv[i]);
        }
        s = blockReduceSum<4>(s, red);
        const float r = rsqrtf(s / (float)HD + 1e-6f);
#pragma unroll
        for (int i = 0; i < 2; i++) {
            f4 wv = ((const f4*)rms1_w)[t + i*256];
            ((f4*)smem)[t + i*256] = xv[i] * r * (wv + 1.0f);
        }
        __syncthreads();
    }

    // ---- P1: in_proj GEMV (1 wave/row, grid-stride) ----
    for (int row = bid*4 + wid; row < PROJN; row += NB*4) {
        const f4* Wr = (const f4*)(in_proj_w + (size_t)row * HD);
        float acc = 0.f;
#pragma unroll
        for (int i = 0; i < 8; i++)
            acc += dot4(ntload(&Wr[lane + i*64]), ((const f4*)smem)[lane + i*64]);
        acc = waveReduceSum(acc);
        if (lane == 0) proj[row] = acc;
    }
    __threadfence();
    grid.sync();
    __threadfence();

    // ---- P2: blocks 0..31 = SSM per head; others prefetch out_proj to L2/LLC ----
    if (bid < NVHD) {
        const int head = bid, qhead = head >> 1;
        float* q_s  = smem;         // 128
        float* k_s  = smem + 128;   // 128
        float* v_s  = smem + 256;   // 128
        float* skr2 = smem + 384;   // 256
        float* sqr2 = smem + 640;   // 256

        float qv = 0.f, kv = 0.f, vv = 0.f;
        if (t < 128) {
            int cq = qhead*KDD + t;
            f4 cs = *(const f4*)(conv_state + (size_t)cq*4);
            f4 w  = *(const f4*)(conv_weight + (size_t)cq*4);
            float xm = proj[cq];
            qv = siluf_(cs.y*w.x + cs.z*w.y + cs.w*w.z + xm*w.w);
            f4 nc; nc.x = cs.y; nc.y = cs.z; nc.z = cs.w; nc.w = xm;
            *(f4*)(new_conv + (size_t)cq*4) = nc;

            int ck = 2048 + qhead*KDD + t;
            cs = *(const f4*)(conv_state + (size_t)ck*4);
            w  = *(const f4*)(conv_weight + (size_t)ck*4);
            xm = proj[ck];
            kv = siluf_(cs.y*w.x + cs.z*w.y + cs.w*w.z + xm*w.w);
            nc.x = cs.y; nc.y = cs.z; nc.z = cs.w; nc.w = xm;
            *(f4*)(new_conv + (size_t)ck*4) = nc;

            int cv = 4096 + head*VDD + t;
            cs = *(const f4*)(conv_state + (size_t)cv*4);
            w  = *(const f4*)(conv_weight + (size_t)cv*4);
            xm = proj[cv];
            vv = siluf_(cs.y*w.x + cs.z*w.y + cs.w*w.z + xm*w.w);
            nc.x = cs.y; nc.y = cs.z; nc.z = cs.w; nc.w = xm;
            *(f4*)(new_conv + (size_t)cv*4) = nc;
        }

        const float sq = blockReduceSum<4>(qv*qv, red);
        const float sk = blockReduceSum<4>(kv*kv, red);
        const float qn = qv / fmaxf(sqrtf(sq), 1e-12f) * 0.08838834764831845f; // *128^-0.5
        const float kn = kv / fmaxf(sqrtf(sk), 1e-12f);
        const float kq = blockReduceSum<4>(qn*kn, red);

        if (t < 128) { q_s[t] = qn; k_s[t] = kn; v_s[t] = vv; }
        __syncthreads();

        const float a_raw = proj[QKVD + TVD + head];
        const float b_raw = proj[QKVD + TVD + NVHD + head];
        const float beta  = sigmoidf_(b_raw);
        const float g     = -expf(A_log[head]) * softplusf_(a_raw + dt_bias[head]);
        const float decay = expf(g);

        const int col = t & 127;
        const int kh  = t >> 7;   // 0 or 1
        const float* Sp = ssm_state + (size_t)head*KDD*VDD + (size_t)kh*64*VDD + col;
        float skr = 0.f, sqr = 0.f;
#pragma unroll 16
        for (int k = 0; k < 64; k++) {
            float sv = Sp[k*VDD];
            skr += sv * k_s[kh*64 + k];
            sqr += sv * q_s[kh*64 + k];
        }
        skr2[t] = skr; sqr2[t] = sqr;
        __syncthreads();
        const float Skr = skr2[col] + skr2[col + 128];
        const float Sqr = sqr2[col] + sqr2[col + 128];
        const float delta = (v_s[col] - decay * Skr) * beta;

        float* Np = new_ssm + (size_t)head*KDD*VDD + (size_t)kh*64*VDD + col;
#pragma unroll 16
        for (int k = 0; k < 64; k++) {
            float sv = Sp[k*VDD];
            Np[k*VDD] = decay * sv + k_s[kh*64 + k] * delta;
        }

        const float y = decay * Sqr + delta * kq;
        const float sy = blockReduceSum<4>((kh == 0) ? y*y : 0.f, red);
        if (t < 128) {
            const float rr = rsqrtf(sy / (float)VDD + 1e-6f);
            const float z  = proj[QKVD + head*VDD + t];
            yout[head*VDD + t] = y * rr * norm_weight[t] * siluf_(z);
        }
    } else {
        // prefetch out_proj_w into cache hierarchy (overlaps SSM latency phase)
        const f4* P = (const f4*)out_proj_w;
        const int n = HD*TVD/4;
        float acc = 0.f;
        for (int i = (bid - NVHD)*BT + t; i < n; i += (NB - NVHD)*BT) {
            f4 v = P[i];
            acc += v.x + v.y + v.z + v.w;
        }
        asm volatile("" :: "v"(acc));   // keep loads live
    }
    __threadfence();
    grid.sync();
    __threadfence();

    // ---- P3: out_proj GEMV + residual -> x1 (2 rows/block, 2-wave split-K) ----
    {
        const int row   = bid*2 + (wid >> 1);   // 0..2047
        const int khalf = wid & 1;
        const f4* Wr = (const f4*)(out_proj_w + (size_t)row * TVD);
        const f4* vr = (const f4*)yout;
        float acc = 0.f;
#pragma unroll
        for (int i = 0; i < 8; i++) {
            int idx = khalf*512 + i*64 + lane;
            acc += dot4(Wr[idx], vr[idx]);   // plain load: prefetched, cache-hot
        }
        acc = waveReduceSum(acc);
        if (lane == 0) part[wid] = acc;
        __syncthreads();
        if (t == 0)   x1[bid*2]   = x[bid*2]   + part[0] + part[1];
        if (t == 128) x1[bid*2+1] = x[bid*2+1] + part[2] + part[3];
    }
    __threadfence();
    grid.sync();
    __threadfence();

    // ---- P4: rms2 prologue (x1 L2-hot) + gate/up dual GEMV ----
    {
        f4 yv[2];
        float s = 0.f;
#pragma unroll
        for (int i = 0; i < 2; i++) {
            yv[i] = ((const f4*)x1)[t + i*256];
            s += dot4(yv[i], yv[i]);
        }
        s = blockReduceSum<4>(s, red);
        const float r = rsqrtf(s / (float)HD + 1e-6f);
#pragma unroll
        for (int i = 0; i < 2; i++) {
            f4 wv = ((const f4*)rms2_w)[t + i*256];
            ((f4*)smem)[t + i*256] = yv[i] * (wv + 1.0f);   // r folded at end
        }
        __syncthreads();

        for (int row = bid*4 + wid; row < 8192; row += NB*4) {
            const f4* Gr = (const f4*)(gate_w + (size_t)row * HD);
            const f4* Ur = (const f4*)(up_w   + (size_t)row * HD);
            float ag = 0.f, au = 0.f;
#pragma unroll
            for (int i = 0; i < 8; i++) {
                f4 tt = ((const f4*)smem)[lane + i*64];
                ag += dot4(ntload(&Gr[lane + i*64]), tt);
                au += dot4(ntload(&Ur[lane + i*64]), tt);
            }
            ag = waveReduceSum(ag);
            au = waveReduceSum(au);
            if (lane == 0) mmid[row] = siluf_(ag * r) * (au * r);
        }
    }
    __threadfence();
    grid.sync();
    __threadfence();

    // ---- P5: down GEMV + residual -> out ----
    {
        const int row   = bid*2 + (wid >> 1);
        const int khalf = wid & 1;
        const f4* Wr = (const f4*)(down_w + (size_t)row * 8192);
        const f4* vr = (const f4*)mmid;
        float acc = 0.f;
#pragma unroll
        for (int i = 0; i < 16; i++) {
            int idx = khalf*1024 + i*64 + lane;
            acc += dot4(ntload(&Wr[idx]), vr[idx]);
        }
        acc = waveReduceSum(acc);
        if (lane == 0) part[wid] = acc;
        __syncthreads();
        if (t == 0)   out0[bid*2]   = x1[bid*2]   + part[0] + part[1];
        if (t == 128) out0[bid*2+1] = x1[bid*2+1] + part[2] + part[3];
    }
}

// ================= fallback: proven 5-kernel path =================
__global__ void kA_inproj(const float* __restrict__ x, const float* __restrict__ w1,
                          const float* __restrict__ W, float* __restrict__ proj) {
    __shared__ float red[4];
    __shared__ float hl[HD];
    const int t = threadIdx.x;
    f4 xv[2];
    float s = 0.f;
#pragma unroll
    for (int i = 0; i < 2; i++) { xv[i] = ((const f4*)x)[t + i*256]; s += dot4(xv[i], xv[i]); }
    s = blockReduceSum<4>(s, red);
    const float r = rsqrtf(s / (float)HD + 1e-6f);
#pragma unroll
    for (int i = 0; i < 2; i++) {
        f4 wv = ((const f4*)w1)[t + i*256];
        ((f4*)hl)[t + i*256] = xv[i] * r * (wv + 1.0f);
    }
    __syncthreads();
    const int wid = t >> 6, lane = t & 63;
    const int row = blockIdx.x * 4 + wid;
    const f4* Wr = (const f4*)(W + (size_t)row * HD);
    float acc = 0.f;
#pragma unroll
    for (int i = 0; i < 8; i++) acc += dot4(ntload(&Wr[lane + i*64]), ((const f4*)hl)[lane + i*64]);
    acc = waveReduceSum(acc);
    if (lane == 0) proj[row] = acc;
}

__global__ void kB_ssm(const float* __restrict__ proj, const float* __restrict__ conv_state,
                       const float* __restrict__ conv_weight, const float* __restrict__ ssm_state,
                       const float* __restrict__ A_log, const float* __restrict__ dt_bias,
                       const float* __restrict__ norm_weight, float* __restrict__ new_conv_state,
                       float* __restrict__ new_ssm, float* __restrict__ yout) {
    const int head = blockIdx.x, t = threadIdx.x, qhead = head >> 1;
    __shared__ float red[4];
    __shared__ float q_s[KDD], k_s[KDD], v_s[VDD];
    __shared__ float skr2[256], sqr2[256];
    float qv = 0.f, kv = 0.f, vv = 0.f;
    if (t < 128) {
        int cq = qhead*KDD + t;
        f4 cs = *(const f4*)(conv_state + (size_t)cq*4);
        f4 w  = *(const f4*)(conv_weight + (size_t)cq*4);
        float xm = proj[cq];
        qv = siluf_(cs.y*w.x + cs.z*w.y + cs.w*w.z + xm*w.w);
        f4 nc; nc.x = cs.y; nc.y = cs.z; nc.z = cs.w; nc.w = xm;
        *(f4*)(new_conv_state + (size_t)cq*4) = nc;
        int ck = 2048 + qhead*KDD + t;
        cs = *(const f4*)(conv_state + (size_t)ck*4);
        w  = *(const f4*)(conv_weight + (size_t)ck*4);
        xm = proj[ck];
        kv = siluf_(cs.y*w.x + cs.z*w.y + cs.w*w.z + xm*w.w);
        nc.x = cs.y; nc.y = cs.z; nc.z = cs.w; nc.w = xm;
        *(f4*)(new_conv_state + (size_t)ck*4) = nc;
        int cv = 4096 + head*VDD + t;
        cs = *(const f4*)(conv_state + (size_t)cv*4);
        w  = *(const f4*)(conv_weight + (size_t)cv*4);
        xm = proj[cv];
        vv = siluf_(cs.y*w.x + cs.z*w.y + cs.w*w.z + xm*w.w);
        nc.x = cs.y; nc.y = cs.z; nc.z = cs.w; nc.w = xm;
        *(f4*)(new_conv_state + (size_t)cv*4) = nc;
    }
    const float sq = blockReduceSum<4>(qv*qv, red);
    const float sk = blockReduceSum<4>(kv*kv, red);
    const float qn = qv / fmaxf(sqrtf(sq), 1e-12f) * 0.08838834764831845f;
    const float kn = kv / fmaxf(sqrtf(sk), 1e-12f);
    const float kq = blockReduceSum<4>(qn*kn, red);
    if (t < 128) { q_s[t] = qn; k_s[t] = kn; v_s[t] = vv; }
    __syncthreads();
    const float a_raw = proj[QKVD + TVD + head];
    const float b_raw = proj[QKVD + TVD + NVHD + head];
    const float beta  = sigmoidf_(b_raw);
    const float g     = -expf(A_log[head]) * softplusf_(a_raw + dt_bias[head]);
    const float decay = expf(g);
    const int col = t & 127, kh = t >> 7;
    const float* Sp = ssm_state + (size_t)head*KDD*VDD + (size_t)kh*64*VDD + col;
    float skr = 0.f, sqr = 0.f;
#pragma unroll 16
    for (int k = 0; k < 64; k++) {
        float sv = Sp[k*VDD];
        skr += sv * k_s[kh*64 + k];
        sqr += sv * q_s[kh*64 + k];
    }
    skr2[t] = skr; sqr2[t] = sqr;
    __syncthreads();
    const float Skr = skr2[col] + skr2[col + 128];
    const float Sqr = sqr2[col] + sqr2[col + 128];
    const float delta = (v_s[col] - decay * Skr) * beta;
    float* Np = new_ssm + (size_t)head*KDD*VDD + (size_t)kh*64*VDD + col;
#pragma unroll 16
    for (int k = 0; k < 64; k++) {
        float sv = Sp[k*VDD];
        Np[k*VDD] = decay * sv + k_s[kh*64 + k] * delta;
    }
    const float y = decay * Sqr + delta * kq;
    const float sy = blockReduceSum<4>((kh == 0) ? y*y : 0.f, red);
    if (t < 128) {
        const float rr = rsqrtf(sy / (float)VDD + 1e-6f);
        const float z  = proj[QKVD + head*VDD + t];
        yout[head*VDD + t] = y * rr * norm_weight[t] * siluf_(z);
    }
}

__global__ void kC_outproj(const float* __restrict__ W, const float* __restrict__ y,
                           const float* __restrict__ x, float* __restrict__ x1) {
    __shared__ float part[4];
    const int t = threadIdx.x, wid = t >> 6, lane = t & 63;
    const int row = blockIdx.x;
    const f4* Wr = (const f4*)(W + (size_t)row * TVD);
    const f4* vr = (const f4*)y;
    float acc = 0.f;
#pragma unroll
    for (int i = 0; i < 4; i++) {
        int idx = wid*256 + i*64 + lane;
        acc += dot4(ntload(&Wr[idx]), vr[idx]);
    }
    acc = waveReduceSum(acc);
    if (lane == 0) part[wid] = acc;
    __syncthreads();
    if (t == 0) x1[row] = x[row] + part[0] + part[1] + part[2] + part[3];
}

__global__ void kD_gateup(const float* __restrict__ GW, const float* __restrict__ UW,
                          const float* __restrict__ x1, const float* __restrict__ w2,
                          float* __restrict__ m) {
    __shared__ float red[4];
    __shared__ float tl[HD];
    const int t = threadIdx.x;
    f4 xv[2];
    float s = 0.f;
#pragma unroll
    for (int i = 0; i < 2; i++) { xv[i] = ((const f4*)x1)[t + i*256]; s += dot4(xv[i], xv[i]); }
    s = blockReduceSum<4>(s, red);
    const float r = rsqrtf(s / (float)HD + 1e-6f);
#pragma unroll
    for (int i = 0; i < 2; i++) {
        f4 wv = ((const f4*)w2)[t + i*256];
        ((f4*)tl)[t + i*256] = xv[i] * (wv + 1.0f);
    }
    __syncthreads();
    const int wid = t >> 6, lane = t & 63;
    const int row = blockIdx.x * 4 + wid;
    const f4* Gr = (const f4*)(GW + (size_t)row * HD);
    const f4* Ur = (const f4*)(UW + (size_t)row * HD);
    float ag = 0.f, au = 0.f;
#pragma unroll
    for (int i = 0; i < 8; i++) {
        f4 tt = ((const f4*)tl)[lane + i*64];
        ag += dot4(ntload(&Gr[lane + i*64]), tt);
        au += dot4(ntload(&Ur[lane + i*64]), tt);
    }
    ag = waveReduceSum(ag);
    au = waveReduceSum(au);
    if (lane == 0) m[row] = siluf_(ag * r) * (au * r);
}

__global__ void kE_down(const float* __restrict__ W, const float* __restrict__ m,
                        const float* __restrict__ x1, float* __restrict__ out0) {
    __shared__ float part[4];
    const int t = threadIdx.x, wid = t >> 6, lane = t & 63;
    const int row = blockIdx.x;
    const f4* Wr = (const f4*)(W + (size_t)row * 8192);
    const f4* vr = (const f4*)m;
    float acc = 0.f;
#pragma unroll
    for (int i = 0; i < 8; i++) {
        int idx = wid*512 + i*64 + lane;
        acc += dot4(ntload(&Wr[idx]), vr[idx]);
    }
    acc = waveReduceSum(acc);
    if (lane == 0) part[wid] = acc;
    __syncthreads();
    if (t == 0) out0[row] = x1[row] + part[0] + part[1] + part[2] + part[3];
}

// ---------- launch ----------
extern "C" void kernel_launch(void* const* d_in, const int* in_sizes, int n_in,
                              void* d_out, int out_size, void* d_ws, size_t ws_size,
                              hipStream_t stream) {
    const float* x           = (const float*)d_in[0];
    const float* conv_state  = (const float*)d_in[1];
    const float* ssm_state   = (const float*)d_in[2];
    const float* in_proj_w   = (const float*)d_in[3];
    const float* out_proj_w  = (const float*)d_in[4];
    const float* conv_weight = (const float*)d_in[5];
    const float* A_log       = (const float*)d_in[6];
    const float* dt_bias     = (const float*)d_in[7];
    const float* norm_weight = (const float*)d_in[8];
    const float* rms1_w      = (const float*)d_in[9];
    const float* rms2_w      = (const float*)d_in[10];
    const float* gate_w      = (const float*)d_in[11];
    const float* up_w        = (const float*)d_in[12];
    const float* down_w      = (const float*)d_in[13];

    float* out0     = (float*)d_out;        // 2048
    float* new_conv = out0 + HD;            // 32768
    float* new_ssm  = new_conv + QKVD*4;    // 524288

    float* ws   = (float*)d_ws;
    float* proj = ws;                 // 12352
    float* yout = proj + PROJN;       // 4096
    float* x1   = yout + TVD;         // 2048
    float* mmid = x1 + HD;            // 8192

    void* kargs[] = {
        (void*)&x, (void*)&conv_state, (void*)&ssm_state, (void*)&in_proj_w,
        (void*)&out_proj_w, (void*)&conv_weight, (void*)&A_log, (void*)&dt_bias,
        (void*)&norm_weight, (void*)&rms1_w, (void*)&rms2_w, (void*)&gate_w,
        (void*)&up_w, (void*)&down_w,
        (void*)&out0, (void*)&new_conv, (void*)&new_ssm,
        (void*)&proj, (void*)&yout, (void*)&x1, (void*)&mmid
    };
    hipError_t e = hipLaunchCooperativeKernel((const void*)mega, dim3(NB), dim3(BT),
                                              kargs, 0, stream);
    if (e != hipSuccess) {
        // fallback: proven 5-kernel path
        (void)hipGetLastError();
        kA_inproj<<<PROJN/4, 256, 0, stream>>>(x, rms1_w, in_proj_w, proj);
        kB_ssm<<<NVHD, 256, 0, stream>>>(proj, conv_state, conv_weight, ssm_state,
                                         A_log, dt_bias, norm_weight,
                                         new_conv, new_ssm, yout);
        kC_outproj<<<HD, 256, 0, stream>>>(out_proj_w, yout, x, x1);
        kD_gateup<<<8192/4, 256, 0, stream>>>(gate_w, up_w, x1, rms2_w, mmid);
        kE_down<<<HD, 256, 0, stream>>>(down_w, mmid, x1, out0);
    }
}

// Round 5
// 322.787 us; speedup vs baseline: 4.8121x; 4.8121x over previous
//
#include <hip/hip_runtime.h>
#include <math.h>

// Problem dims
#define HD    2048
#define QKVD  8192
#define TVD   4096
#define NVHD  32
#define KDD   128
#define VDD   128
#define PROJN (QKVD + TVD + 2*NVHD)   // 12352

typedef float f4 __attribute__((ext_vector_type(4)));

// ---------- helpers ----------
__device__ __forceinline__ float sigmoidf_(float x) { return 1.0f / (1.0f + expf(-x)); }
__device__ __forceinline__ float siluf_(float x)    { return x / (1.0f + expf(-x)); }
__device__ __forceinline__ float softplusf_(float x){ return (x > 20.0f) ? x : log1pf(expf(x)); }
__device__ __forceinline__ float dot4(f4 a, f4 b)   { return a.x*b.x + a.y*b.y + a.z*b.z + a.w*b.w; }
__device__ __forceinline__ f4 ntload(const f4* p)   { return __builtin_nontemporal_load(p); }

__device__ __forceinline__ float waveReduceSum(float v) {
#pragma unroll
    for (int o = 32; o > 0; o >>= 1) v += __shfl_down(v, o, 64);
    return v;   // total valid in lane 0
}

template<int NW>
__device__ __forceinline__ float blockReduceSum(float v, float* red) {
    const int lane = threadIdx.x & 63, wid = threadIdx.x >> 6;
    v = waveReduceSum(v);
    if (lane == 0) red[wid] = v;
    __syncthreads();
    float s = 0.f;
#pragma unroll
    for (int w = 0; w < NW; w++) s += red[w];
    __syncthreads();
    return s;
}

// ---------- K_A: rms1 folded into in_proj GEMV; barrier-free, 1 wave/row ----------
// proj[row] = r * dot(W[row,:], x*(1+w1)),  r = rsqrt(mean(x^2)+eps)
__global__ void kA_inproj(const float* __restrict__ x, const float* __restrict__ w1,
                          const float* __restrict__ W, float* __restrict__ proj) {
    const int t = threadIdx.x, wid = t >> 6, lane = t & 63;
    const int row = blockIdx.x * 4 + wid;

    f4 tt[8];
    float ss = 0.f;
#pragma unroll
    for (int i = 0; i < 8; i++) {             // x,w1 are 8KB each: L2-hot
        f4 xv = ((const f4*)x)[lane + i*64];
        f4 wv = ((const f4*)w1)[lane + i*64];
        ss += dot4(xv, xv);
        tt[i] = xv * (wv + 1.0f);
    }
    const f4* Wr = (const f4*)(W + (size_t)row * HD);
    float acc = 0.f;
#pragma unroll
    for (int i = 0; i < 8; i++)
        acc += dot4(ntload(&Wr[lane + i*64]), tt[i]);
    acc = waveReduceSum(acc);
    ss  = waveReduceSum(ss);
    if (lane == 0) proj[row] = acc * rsqrtf(ss / (float)HD + 1e-6f);
}

// ---------- K_B: conv update + L2 norms + gated delta-rule + y-gate (512 thr) ----------
__global__ void kB_ssm(const float* __restrict__ proj,
                       const float* __restrict__ conv_state,
                       const float* __restrict__ conv_weight,
                       const float* __restrict__ ssm_state,
                       const float* __restrict__ A_log,
                       const float* __restrict__ dt_bias,
                       const float* __restrict__ norm_weight,
                       float* __restrict__ new_conv_state,
                       float* __restrict__ new_ssm,
                       float* __restrict__ yout) {
    const int head  = blockIdx.x;     // 0..31
    const int t     = threadIdx.x;    // 0..511
    const int qhead = head >> 1;      // ratio = 2

    __shared__ float red[8];
    __shared__ float q_s[KDD], k_s[KDD], v_s[VDD];
    __shared__ float skr2[512], sqr2[512];

    float qv = 0.f, kv = 0.f, vv = 0.f;
    if (t < 128) {
        int cq = qhead*KDD + t;
        f4 cs = *(const f4*)(conv_state + (size_t)cq*4);
        f4 w  = *(const f4*)(conv_weight + (size_t)cq*4);
        float xm = proj[cq];
        qv = siluf_(cs.y*w.x + cs.z*w.y + cs.w*w.z + xm*w.w);
        f4 nc; nc.x = cs.y; nc.y = cs.z; nc.z = cs.w; nc.w = xm;
        *(f4*)(new_conv_state + (size_t)cq*4) = nc;

        int ck = 2048 + qhead*KDD + t;
        cs = *(const f4*)(conv_state + (size_t)ck*4);
        w  = *(const f4*)(conv_weight + (size_t)ck*4);
        xm = proj[ck];
        kv = siluf_(cs.y*w.x + cs.z*w.y + cs.w*w.z + xm*w.w);
        nc.x = cs.y; nc.y = cs.z; nc.z = cs.w; nc.w = xm;
        *(f4*)(new_conv_state + (size_t)ck*4) = nc;

        int cv = 4096 + head*VDD + t;
        cs = *(const f4*)(conv_state + (size_t)cv*4);
        w  = *(const f4*)(conv_weight + (size_t)cv*4);
        xm = proj[cv];
        vv = siluf_(cs.y*w.x + cs.z*w.y + cs.w*w.z + xm*w.w);
        nc.x = cs.y; nc.y = cs.z; nc.z = cs.w; nc.w = xm;
        *(f4*)(new_conv_state + (size_t)cv*4) = nc;
    }

    const float sq = blockReduceSum<8>(qv*qv, red);
    const float sk = blockReduceSum<8>(kv*kv, red);
    const float qn = qv / fmaxf(sqrtf(sq), 1e-12f) * 0.08838834764831845f; // * 128^-0.5
    const float kn = kv / fmaxf(sqrtf(sk), 1e-12f);
    const float kq = blockReduceSum<8>(qn*kn, red);

    if (t < 128) { q_s[t] = qn; k_s[t] = kn; v_s[t] = vv; }
    __syncthreads();

    const float a_raw = proj[QKVD + TVD + head];
    const float b_raw = proj[QKVD + TVD + NVHD + head];
    const float beta  = sigmoidf_(b_raw);
    const float g     = -expf(A_log[head]) * softplusf_(a_raw + dt_bias[head]);
    const float decay = expf(g);

    const int col = t & 127;
    const int kh  = t >> 7;                // 0..3
    const float* Sp = ssm_state + (size_t)head*KDD*VDD + (size_t)kh*32*VDD + col;
    float skr = 0.f, sqr = 0.f;
#pragma unroll 8
    for (int k = 0; k < 32; k++) {
        float sv = Sp[k*VDD];
        skr += sv * k_s[kh*32 + k];
        sqr += sv * q_s[kh*32 + k];
    }
    skr2[t] = skr; sqr2[t] = sqr;
    __syncthreads();
    const float Skr = skr2[col] + skr2[col+128] + skr2[col+256] + skr2[col+384];
    const float Sqr = sqr2[col] + sqr2[col+128] + sqr2[col+256] + sqr2[col+384];
    const float delta = (v_s[col] - decay * Skr) * beta;

    float* Np = new_ssm + (size_t)head*KDD*VDD + (size_t)kh*32*VDD + col;
#pragma unroll 8
    for (int k = 0; k < 32; k++) {
        float sv = Sp[k*VDD];
        Np[k*VDD] = decay * sv + k_s[kh*32 + k] * delta;
    }

    const float y = decay * Sqr + delta * kq;
    const float sy = blockReduceSum<8>((kh == 0) ? y*y : 0.f, red);
    if (t < 128) {
        const float rr = rsqrtf(sy / (float)VDD + 1e-6f);
        const float z  = proj[QKVD + head*VDD + t];
        yout[head*VDD + t] = y * rr * norm_weight[t] * siluf_(z);
    }
}

// ---------- K_C: out_proj GEMV + residual; barrier-free, 1 wave/row ----------
__global__ void kC_outproj(const float* __restrict__ W, const float* __restrict__ y,
                           const float* __restrict__ x, float* __restrict__ x1) {
    const int t = threadIdx.x, wid = t >> 6, lane = t & 63;
    const int row = blockIdx.x * 4 + wid;
    const f4* Wr = (const f4*)(W + (size_t)row * TVD);
    const f4* vr = (const f4*)y;              // 16KB, L2-hot
    float acc = 0.f;
#pragma unroll 8
    for (int i = 0; i < 16; i++)
        acc += dot4(ntload(&Wr[lane + i*64]), vr[lane + i*64]);
    acc = waveReduceSum(acc);
    if (lane == 0) x1[row] = x[row] + acc;
}

// ---------- K_D: rms2 folded into gate/up dual GEMV; barrier-free, 1 wave/row ----------
__global__ void kD_gateup(const float* __restrict__ GW, const float* __restrict__ UW,
                          const float* __restrict__ x1, const float* __restrict__ w2,
                          float* __restrict__ m) {
    const int t = threadIdx.x, wid = t >> 6, lane = t & 63;
    const int row = blockIdx.x * 4 + wid;

    f4 tt[8];
    float ss = 0.f;
#pragma unroll
    for (int i = 0; i < 8; i++) {             // x1,w2: 8KB each, L2-hot
        f4 xv = ((const f4*)x1)[lane + i*64];
        f4 wv = ((const f4*)w2)[lane + i*64];
        ss += dot4(xv, xv);
        tt[i] = xv * (wv + 1.0f);
    }
    const f4* Gr = (const f4*)(GW + (size_t)row * HD);
    const f4* Ur = (const f4*)(UW + (size_t)row * HD);
    float ag = 0.f, au = 0.f;
#pragma unroll 4
    for (int i = 0; i < 8; i++) {
        ag += dot4(ntload(&Gr[lane + i*64]), tt[i]);
        au += dot4(ntload(&Ur[lane + i*64]), tt[i]);
    }
    ag = waveReduceSum(ag);
    au = waveReduceSum(au);
    ss = waveReduceSum(ss);
    if (lane == 0) {
        const float r = rsqrtf(ss / (float)HD + 1e-6f);
        m[row] = siluf_(ag * r) * (au * r);
    }
}

// ---------- K_E: down GEMV + residual; barrier-free, 1 wave/row ----------
__global__ void kE_down(const float* __restrict__ W, const float* __restrict__ m,
                        const float* __restrict__ x1, float* __restrict__ out0) {
    const int t = threadIdx.x, wid = t >> 6, lane = t & 63;
    const int row = blockIdx.x * 4 + wid;
    const f4* Wr = (const f4*)(W + (size_t)row * 8192);
    const f4* vr = (const f4*)m;              // 32KB, L2-hot
    float acc = 0.f;
#pragma unroll 8
    for (int i = 0; i < 32; i++)
        acc += dot4(ntload(&Wr[lane + i*64]), vr[lane + i*64]);
    acc = waveReduceSum(acc);
    if (lane == 0) out0[row] = x1[row] + acc;
}

// ---------- launch ----------
extern "C" void kernel_launch(void* const* d_in, const int* in_sizes, int n_in,
                              void* d_out, int out_size, void* d_ws, size_t ws_size,
                              hipStream_t stream) {
    const float* x           = (const float*)d_in[0];
    const float* conv_state  = (const float*)d_in[1];
    const float* ssm_state   = (const float*)d_in[2];
    const float* in_proj_w   = (const float*)d_in[3];
    const float* out_proj_w  = (const float*)d_in[4];
    const float* conv_weight = (const float*)d_in[5];
    const float* A_log       = (const float*)d_in[6];
    const float* dt_bias     = (const float*)d_in[7];
    const float* norm_weight = (const float*)d_in[8];
    const float* rms1_w      = (const float*)d_in[9];
    const float* rms2_w      = (const float*)d_in[10];
    const float* gate_w      = (const float*)d_in[11];
    const float* up_w        = (const float*)d_in[12];
    const float* down_w      = (const float*)d_in[13];

    float* out0     = (float*)d_out;        // 2048
    float* new_conv = out0 + HD;            // 32768
    float* new_ssm  = new_conv + QKVD*4;    // 524288

    float* ws   = (float*)d_ws;
    float* proj = ws;                 // 12352
    float* yout = proj + PROJN;       // 4096
    float* x1   = yout + TVD;         // 2048
    float* mmid = x1 + HD;            // 8192

    kA_inproj<<<PROJN/4, 256, 0, stream>>>(x, rms1_w, in_proj_w, proj);
    kB_ssm<<<NVHD, 512, 0, stream>>>(proj, conv_state, conv_weight, ssm_state,
                                     A_log, dt_bias, norm_weight,
                                     new_conv, new_ssm, yout);
    kC_outproj<<<HD/4, 256, 0, stream>>>(out_proj_w, yout, x, x1);
    kD_gateup<<<8192/4, 256, 0, stream>>>(gate_w, up_w, x1, rms2_w, mmid);
    kE_down<<<HD/4, 256, 0, stream>>>(down_w, mmid, x1, out0);
}